// Round 7
// baseline (606.636 us; speedup 1.0000x reference)
//
#include <hip/hip_runtime.h>

#define S_LEN 4096
#define DHEAD 64
#define BK    64       // K/V rows per tile
#define NT    (S_LEN / BK)
#define NBH   16
#define KPAD  72       // fp32 fallback kernel only
#define BQ    128      // fp32 fallback kernel only
#define TILE_HALFS (BK * DHEAD)   // 4096 halfs / floats per tile

typedef __fp16   pk16x2 __attribute__((ext_vector_type(2)));
typedef _Float16 half4v __attribute__((ext_vector_type(4)));
typedef _Float16 half8  __attribute__((ext_vector_type(8)));
typedef float    f32x4  __attribute__((ext_vector_type(4)));
typedef float    f32x16 __attribute__((ext_vector_type(16)));
typedef unsigned uint2v __attribute__((ext_vector_type(2)));

#define MFMA32(a, b, c) __builtin_amdgcn_mfma_f32_32x32x16_f16(a, b, c, 0, 0, 0)

__device__ __forceinline__ unsigned pk2u(float a, float b) {
    union { pk16x2 p; unsigned u; } x;
    x.p = __builtin_amdgcn_cvt_pkrtz(a, b);
    return x.u;
}

// permlane32_swap(x,y): r.x[l] = l<32 ? x[l] : y[l-32] ; r.y[l] = l<32 ? x[l+32] : y[l]
__device__ __forceinline__ uint2v pls(unsigned x, unsigned y) {
    return __builtin_amdgcn_permlane32_swap(x, y, false, false);
}
__device__ __forceinline__ float xmax32(float v) {
    uint2v r = pls(__float_as_uint(v), __float_as_uint(v));
    return fmaxf(__uint_as_float(r.x), __uint_as_float(r.y));
}
__device__ __forceinline__ float xadd32(float v) {
    uint2v r = pls(__float_as_uint(v), __float_as_uint(v));
    return __uint_as_float(r.x) + __uint_as_float(r.y);
}

// ---------------------------------------------------------------------------
// Mask scan: is the mask anywhere nonzero?
// ---------------------------------------------------------------------------
__global__ void mask_flag_kernel(const float4* __restrict__ mask, int* __restrict__ flag) {
    const long stride = 2048L * 256;
    long i = (long)blockIdx.x * 256 + threadIdx.x;
    int nz = 0;
    #pragma unroll
    for (int it = 0; it < 8; ++it) {
        float4 a = mask[i + it * stride];
        nz |= (a.x != 0.f) | (a.y != 0.f) | (a.z != 0.f) | (a.w != 0.f);
    }
    if (__any(nz)) {
        if ((threadIdx.x & 63) == 0) atomicOr(flag, 1);
    }
}

// ---------------------------------------------------------------------------
// Attention, ONE pass over fp32 K/V (no conv kernel): 512-thread blocks,
// in-block KV-split (waves 0-3 half A, 4-7 half B), inline fp32->fp16 staging
// into the swizzled LDS images, r3-verified 32x32 inner loop (pls-direct PV,
// THR=8 defer-max, VALU l-sums), in-LDS merge (no fences / atomics / combine).
//   KT[r][chunk c] = K[r][8*(c ^ (r&7)) .. +8]
//   VT[d][chunk c] = V[8*(c ^ (d&7) ^ (d>>3 &7)) + j][d]   (key spreads writes)
// LDS 64 KB -> 2 blocks/CU (16 waves/CU).
// ---------------------------------------------------------------------------
__global__ __launch_bounds__(512, 4) void attn32f_kernel(
    const float* __restrict__ Q, const float* __restrict__ K,
    const float* __restrict__ V, const int* __restrict__ dkp,
    const float* __restrict__ mask, const int* __restrict__ maskflag,
    float* __restrict__ O)
{
    const int bid = blockIdx.x;
    const int L   = (bid & 7) * 64 + (bid >> 3);   // XCD-contiguous decode
    const int bh  = L >> 5;
    const int qt  = L & 31;

    const int tid  = threadIdx.x;
    const int hf   = tid >> 8;          // KV half (0: kt 0..31, 1: kt 32..63)
    const int t    = tid & 255;         // tid within half
    const int w    = (tid >> 6) & 3;    // wave within half
    const int lane = tid & 63;
    const int l31  = lane & 31;
    const int h    = lane >> 5;
    const int cx   = lane & 7;                       // K read key
    const int vkey = (l31 ^ (l31 >> 3)) & 7;         // V read key (row l31)

    const int HT  = NT / 2;             // 32 tiles per half
    const int kt0 = hf * HT;

    const long gbase = (long)bh * S_LEN * DHEAD;
    const float* Qh = Q + gbase;
    const float* Kh = K + gbase;
    const float* Vh = V + gbase;

    const int q0 = qt * 128 + w * 32;
    const float csq  = rsqrtf((float)dkp[0]) * 1.44269504088896f;
    const float mfac = -1e9f * 1.44269504088896f;
    const bool use_mask = (maskflag[0] != 0);

    __shared__ __align__(16) _Float16 KT[2][2][TILE_HALFS];   // [hf][buf] 32 KB
    __shared__ __align__(16) _Float16 VT[2][2][TILE_HALFS];   // [hf][buf] 32 KB

    // ---- Q B-operand frags, pre-scaled ----
    half8 qf[4];
    #pragma unroll
    for (int ks = 0; ks < 4; ++ks) {
        const float4* src = (const float4*)(Qh + (long)(q0 + l31) * DHEAD + ks * 16 + h * 8);
        float4 a = src[0], b = src[1];
        union { unsigned u[4]; half8 h8; } u;
        u.u[0] = pk2u(a.x * csq, a.y * csq);
        u.u[1] = pk2u(a.z * csq, a.w * csq);
        u.u[2] = pk2u(b.x * csq, b.y * csq);
        u.u[3] = pk2u(b.z * csq, b.w * csq);
        qf[ks] = u.h8;
    }

    // ---- staging roles (within half) ----
    const int kr  = t >> 2;             // K row 0..63
    const int ks4 = t & 3;              // K 16-float segment
    const int vrp = t >> 3;             // V row-pair 0..31
    const int vdq = t & 7;              // V d-octet 0..7
    const float* Kb = Kh + (long)kr * DHEAD + ks4 * 16;
    const float* Vb = Vh + (long)(2 * vrp) * DHEAD + vdq * 8;
    const int kcol0 = (((2 * ks4)     ^ (kr & 7)) << 3);
    const int kcol1 = (((2 * ks4 + 1) ^ (kr & 7)) << 3);
    const int vd0   = vdq * 8;
    const int voct  = vrp >> 2;         // V row-octet
    const int vlow  = (2 * vrp) & 7;    // position within chunk

    float4 kf[4], vf[4];
    auto load_tile = [&](int kt) {
        const float4* kp  = (const float4*)(Kb + (long)kt * TILE_HALFS);
        kf[0] = kp[0]; kf[1] = kp[1]; kf[2] = kp[2]; kf[3] = kp[3];
        const float4* vp0 = (const float4*)(Vb + (long)kt * TILE_HALFS);
        const float4* vp1 = (const float4*)(Vb + (long)kt * TILE_HALFS + DHEAD);
        vf[0] = vp0[0]; vf[1] = vp0[1]; vf[2] = vp1[0]; vf[3] = vp1[1];
    };
    auto store_tile = [&](int bb) {
        union { unsigned u[4]; half8 h8; } u0, u1;
        u0.u[0] = pk2u(kf[0].x, kf[0].y);
        u0.u[1] = pk2u(kf[0].z, kf[0].w);
        u0.u[2] = pk2u(kf[1].x, kf[1].y);
        u0.u[3] = pk2u(kf[1].z, kf[1].w);
        u1.u[0] = pk2u(kf[2].x, kf[2].y);
        u1.u[1] = pk2u(kf[2].z, kf[2].w);
        u1.u[2] = pk2u(kf[3].x, kf[3].y);
        u1.u[3] = pk2u(kf[3].z, kf[3].w);
        *(half8*)&KT[hf][bb][kr * 64 + kcol0] = u0.h8;
        *(half8*)&KT[hf][bb][kr * 64 + kcol1] = u1.h8;
        _Float16* vt = &VT[hf][bb][0];
        #define VCOL(j) ((((voct ^ (j) ^ vdq) & 7) << 3) + vlow)
        *(pk16x2*)&vt[(vd0 + 0) * 64 + VCOL(0)] = __builtin_amdgcn_cvt_pkrtz(vf[0].x, vf[2].x);
        *(pk16x2*)&vt[(vd0 + 1) * 64 + VCOL(1)] = __builtin_amdgcn_cvt_pkrtz(vf[0].y, vf[2].y);
        *(pk16x2*)&vt[(vd0 + 2) * 64 + VCOL(2)] = __builtin_amdgcn_cvt_pkrtz(vf[0].z, vf[2].z);
        *(pk16x2*)&vt[(vd0 + 3) * 64 + VCOL(3)] = __builtin_amdgcn_cvt_pkrtz(vf[0].w, vf[2].w);
        *(pk16x2*)&vt[(vd0 + 4) * 64 + VCOL(4)] = __builtin_amdgcn_cvt_pkrtz(vf[1].x, vf[3].x);
        *(pk16x2*)&vt[(vd0 + 5) * 64 + VCOL(5)] = __builtin_amdgcn_cvt_pkrtz(vf[1].y, vf[3].y);
        *(pk16x2*)&vt[(vd0 + 6) * 64 + VCOL(6)] = __builtin_amdgcn_cvt_pkrtz(vf[1].z, vf[3].z);
        *(pk16x2*)&vt[(vd0 + 7) * 64 + VCOL(7)] = __builtin_amdgcn_cvt_pkrtz(vf[1].w, vf[3].w);
        #undef VCOL
    };

    f32x16 o0 = {0.f,0.f,0.f,0.f,0.f,0.f,0.f,0.f,0.f,0.f,0.f,0.f,0.f,0.f,0.f,0.f};
    f32x16 o1 = o0;
    float m_i = -INFINITY;
    float l_i = 0.0f;

    load_tile(kt0);
    store_tile(0);
    __syncthreads();

    for (int lt = 0; lt < HT; ++lt) {
        const int kt = kt0 + lt;
        const int b  = lt & 1;
        if (lt + 1 < HT) load_tile(kt + 1);   // global prefetch overlaps compute

        // ---- S^T = K . Q^T ----
        f32x16 s0 = {0.f,0.f,0.f,0.f,0.f,0.f,0.f,0.f,0.f,0.f,0.f,0.f,0.f,0.f,0.f,0.f};
        f32x16 s1 = s0;
        __builtin_amdgcn_s_setprio(1);
        #pragma unroll
        for (int ks = 0; ks < 4; ++ks) {
            const int off = (((2 * ks + h) ^ cx) << 3);
            half8 a0 = *(const half8*)&KT[hf][b][(l31 << 6) + off];
            half8 a1 = *(const half8*)&KT[hf][b][2048 + (l31 << 6) + off];
            s0 = MFMA32(a0, qf[ks], s0);
            s1 = MFMA32(a1, qf[ks], s1);
        }
        __builtin_amdgcn_s_setprio(0);

        if (use_mask) {
            const float* mrow = mask + (long)(q0 + l31) * S_LEN + kt * BK;
            #pragma unroll
            for (int r = 0; r < 16; ++r) {
                const int k = (r & 3) + ((r >> 2) << 3) + (h << 2);
                s0[r] += mfac * mrow[k];
                s1[r] += mfac * mrow[32 + k];
            }
        }

        // ---- online softmax, THR=8 defer-max ----
        {
            float tt[8];
            #pragma unroll
            for (int i = 0; i < 8; ++i)
                tt[i] = fmaxf(fmaxf(s0[2*i], s0[2*i+1]), fmaxf(s1[2*i], s1[2*i+1]));
            float mx = fmaxf(fmaxf(fmaxf(tt[0], tt[1]), fmaxf(tt[2], tt[3])),
                             fmaxf(fmaxf(tt[4], tt[5]), fmaxf(tt[6], tt[7])));
            mx = xmax32(mx);
            const bool need = __any(mx > m_i + 8.0f);
            const float mnew = need ? fmaxf(m_i, mx) : m_i;
            float ra = 0.f, rb = 0.f;
            #pragma unroll
            for (int r = 0; r < 16; ++r) {
                float p0 = __builtin_amdgcn_exp2f(s0[r] - mnew);
                float p1 = __builtin_amdgcn_exp2f(s1[r] - mnew);
                s0[r] = p0; s1[r] = p1;
                ra += p0; rb += p1;
            }
            float rsum = xadd32(ra + rb);
            if (need) {
                const float alpha = __builtin_amdgcn_exp2f(m_i - mnew);
                #pragma unroll
                for (int r = 0; r < 16; ++r) {
                    const int qr = (r & 3) + ((r >> 2) << 3) + (h << 2);
                    float a_r = __shfl(alpha, qr, 64);
                    o0[r] *= a_r; o1[r] *= a_r;
                }
                l_i = alpha * l_i + rsum;
                m_i = mnew;
            } else {
                l_i += rsum;
            }
        }

        // ---- P words -> PV A-operand via direct pls ----
        unsigned wp[16];
        #pragma unroll
        for (int d = 0; d < 8; ++d) {
            wp[d]     = pk2u(s0[2*d], s0[2*d+1]);
            wp[8 + d] = pk2u(s1[2*d], s1[2*d+1]);
        }

        __builtin_amdgcn_s_setprio(1);
        #pragma unroll
        for (int si = 0; si < 4; ++si) {
            const int bs = (si >> 1) * 8 + (si & 1) * 4;
            uint2v r0 = pls(wp[bs + 0], wp[bs + 2]);
            uint2v r1 = pls(wp[bs + 1], wp[bs + 3]);
            union { unsigned u[4]; half8 h8; } pa;
            pa.u[0] = r0.x; pa.u[1] = r1.x; pa.u[2] = r0.y; pa.u[3] = r1.y;
            const int voff = (((2 * si + h) ^ vkey) << 3);
            half8 v0 = *(const half8*)&VT[hf][b][(l31 << 6) + voff];
            half8 v1 = *(const half8*)&VT[hf][b][2048 + (l31 << 6) + (voff ^ 32)];
            o0 = MFMA32(pa.h8, v0, o0);
            o1 = MFMA32(pa.h8, v1, o1);
        }
        __builtin_amdgcn_s_setprio(0);

        if (lt + 1 < HT) {
            store_tile(b ^ 1);      // buffer not read this iter; all readers synced
            __syncthreads();
        }
    }

    // ---- in-block merge of the two halves (LDS + __syncthreads only) ----
    float*  comb = (float*)&KT[0][0][0];     // [w][row 0..31][col 0..63] = 32 KB
    float2* mlA  = (float2*)&VT[0][0][0];    // half A (m,l): [w*32+row]
    float2* mlB  = mlA + 128;                // half B (m,l)

    __syncthreads();                          // all tile compute done
    if (hf == 1) {
        #pragma unroll
        for (int r = 0; r < 16; ++r) {
            const int qr = (r & 3) + ((r >> 2) << 3) + (h << 2);
            comb[w * 2048 + qr * 64 + l31]      = o0[r];
            comb[w * 2048 + qr * 64 + 32 + l31] = o1[r];
        }
        if (h == 0) mlB[w * 32 + l31] = make_float2(m_i, l_i);
    } else {
        if (h == 0) mlA[w * 32 + l31] = make_float2(m_i, l_i);
    }
    __syncthreads();

    if (hf == 0) {
        float* dst = O + gbase;
        #pragma unroll
        for (int r = 0; r < 16; ++r) {
            const int qr = (r & 3) + ((r >> 2) << 3) + (h << 2);
            const float2 ml1 = mlA[w * 32 + qr];
            const float2 ml2 = mlB[w * 32 + qr];
            const float m   = fmaxf(ml1.x, ml2.x);
            const float a1  = __builtin_amdgcn_exp2f(ml1.x - m);
            const float a2  = __builtin_amdgcn_exp2f(ml2.x - m);
            const float inv = __builtin_amdgcn_rcpf(ml1.y * a1 + ml2.y * a2);
            const float p0  = comb[w * 2048 + qr * 64 + l31];
            const float p1  = comb[w * 2048 + qr * 64 + 32 + l31];
            const long row = (long)(q0 + qr) * DHEAD;
            dst[row + l31]      = (o0[r] * a1 + p0 * a2) * inv;
            dst[row + 32 + l31] = (o1[r] * a1 + p1 * a2) * inv;
        }
    }
}

// ---------------------------------------------------------------------------
// Tiny-ws fallback: verified fp32-input kernel, verbatim.
// ---------------------------------------------------------------------------
__global__ __launch_bounds__(256, 2) void attn_kernel_fb(
    const float* __restrict__ Q, const float* __restrict__ K,
    const float* __restrict__ V, const int* __restrict__ dk,
    const float* __restrict__ mask, const int* __restrict__ maskflag,
    float* __restrict__ O)
{
    const int qt   = blockIdx.x;
    const int bh   = blockIdx.y;
    const int tid  = threadIdx.x;
    const int wave = tid >> 6;
    const int lane = tid & 63;
    const int l15  = lane & 15;
    const int quad = lane >> 4;

    const long base = (long)bh * S_LEN * DHEAD;
    const float* Qh = Q + base;
    const float* Kh = K + base;
    const float* Vh = V + base;
    float*       Oh = O + base;

    const int q0 = qt * BQ + wave * 32;
    const float csq  = rsqrtf((float)dk[0]) * 1.44269504088896f;
    const float mfac = -1e9f * 1.44269504088896f;
    const bool use_mask = (maskflag[0] != 0);

    __shared__ __align__(16) _Float16 Kt[2][BK][KPAD];
    __shared__ __align__(16) _Float16 Vt[2][DHEAD * KPAD];
    __shared__ __align__(16) _Float16 Pw[4][32][KPAD];

    half8 qf[2][2];
    #pragma unroll
    for (int f = 0; f < 2; ++f) {
        #pragma unroll
        for (int kc = 0; kc < 2; ++kc) {
            const float4* src = (const float4*)(Qh + (long)(q0 + f*16 + l15) * DHEAD + kc*32 + quad*8);
            float4 a = src[0], b = src[1];
            union { pk16x2 p[4]; half8 h; } u;
            u.p[0] = __builtin_amdgcn_cvt_pkrtz(a.x*csq, a.y*csq);
            u.p[1] = __builtin_amdgcn_cvt_pkrtz(a.z*csq, a.w*csq);
            u.p[2] = __builtin_amdgcn_cvt_pkrtz(b.x*csq, b.y*csq);
            u.p[3] = __builtin_amdgcn_cvt_pkrtz(b.z*csq, b.w*csq);
            qf[f][kc] = u.h;
        }
    }

    const int kr  = tid >> 2;
    const int ks  = tid & 3;
    const int vrp = tid >> 3;
    const int vdq = tid & 7;
    const float* Kb = Kh + (long)kr * DHEAD + ks * 16;
    const float* Vb = Vh + (long)(2 * vrp) * DHEAD + vdq * 8;
    const int vcol = (((vrp >> 2) ^ vdq) << 3) + ((2 * vrp) & 7);
    const int vd0  = vdq * 8;

    float4 kf[4], vf[4];
    auto load_tile = [&](int kt) {
        const float4* kp  = (const float4*)(Kb + (long)kt * BK * DHEAD);
        kf[0] = kp[0]; kf[1] = kp[1]; kf[2] = kp[2]; kf[3] = kp[3];
        const float4* vp0 = (const float4*)(Vb + (long)kt * BK * DHEAD);
        const float4* vp1 = (const float4*)(Vb + (long)kt * BK * DHEAD + DHEAD);
        vf[0] = vp0[0]; vf[1] = vp0[1]; vf[2] = vp1[0]; vf[3] = vp1[1];
    };
    auto store_tile = [&](int b) {
        union { pk16x2 p[4]; half8 h; } u0, u1;
        u0.p[0] = __builtin_amdgcn_cvt_pkrtz(kf[0].x, kf[0].y);
        u0.p[1] = __builtin_amdgcn_cvt_pkrtz(kf[0].z, kf[0].w);
        u0.p[2] = __builtin_amdgcn_cvt_pkrtz(kf[1].x, kf[1].y);
        u0.p[3] = __builtin_amdgcn_cvt_pkrtz(kf[1].z, kf[1].w);
        u1.p[0] = __builtin_amdgcn_cvt_pkrtz(kf[2].x, kf[2].y);
        u1.p[1] = __builtin_amdgcn_cvt_pkrtz(kf[2].z, kf[2].w);
        u1.p[2] = __builtin_amdgcn_cvt_pkrtz(kf[3].x, kf[3].y);
        u1.p[3] = __builtin_amdgcn_cvt_pkrtz(kf[3].z, kf[3].w);
        *(half8*)&Kt[b][kr][ks*16]     = u0.h;
        *(half8*)&Kt[b][kr][ks*16 + 8] = u1.h;
        _Float16* vt = &Vt[b][0];
        *(pk16x2*)&vt[(vd0+0)*KPAD + vcol] = __builtin_amdgcn_cvt_pkrtz(vf[0].x, vf[2].x);
        *(pk16x2*)&vt[(vd0+1)*KPAD + vcol] = __builtin_amdgcn_cvt_pkrtz(vf[0].y, vf[2].y);
        *(pk16x2*)&vt[(vd0+2)*KPAD + vcol] = __builtin_amdgcn_cvt_pkrtz(vf[0].z, vf[2].z);
        *(pk16x2*)&vt[(vd0+3)*KPAD + vcol] = __builtin_amdgcn_cvt_pkrtz(vf[0].w, vf[2].w);
        *(pk16x2*)&vt[(vd0+4)*KPAD + vcol] = __builtin_amdgcn_cvt_pkrtz(vf[1].x, vf[3].x);
        *(pk16x2*)&vt[(vd0+5)*KPAD + vcol] = __builtin_amdgcn_cvt_pkrtz(vf[1].y, vf[3].y);
        *(pk16x2*)&vt[(vd0+6)*KPAD + vcol] = __builtin_amdgcn_cvt_pkrtz(vf[1].z, vf[3].z);
        *(pk16x2*)&vt[(vd0+7)*KPAD + vcol] = __builtin_amdgcn_cvt_pkrtz(vf[1].w, vf[3].w);
    };

    f32x4 o[2][4];
    #pragma unroll
    for (int f = 0; f < 2; ++f)
        #pragma unroll
        for (int dt = 0; dt < 4; ++dt) o[f][dt] = (f32x4){0.f, 0.f, 0.f, 0.f};
    float m_i[2] = {-INFINITY, -INFINITY};
    float l_i[2] = {0.0f, 0.0f};

    load_tile(0);
    store_tile(0);
    __syncthreads();

    for (int kt = 0; kt < NT; ++kt) {
        const int b = kt & 1;
        if (kt + 1 < NT) load_tile(kt + 1);

        f32x4 st[2][4];
        #pragma unroll
        for (int f = 0; f < 2; ++f)
            #pragma unroll
            for (int nt = 0; nt < 4; ++nt) st[f][nt] = (f32x4){0.f,0.f,0.f,0.f};
        #pragma unroll
        for (int nt = 0; nt < 4; ++nt) {
            #pragma unroll
            for (int kc = 0; kc < 2; ++kc) {
                half8 af = *(const half8*)&Kt[b][nt*16 + l15][kc*32 + quad*8];
                st[0][nt] = __builtin_amdgcn_mfma_f32_16x16x32_f16(af, qf[0][kc], st[0][nt], 0, 0, 0);
                st[1][nt] = __builtin_amdgcn_mfma_f32_16x16x32_f16(af, qf[1][kc], st[1][nt], 0, 0, 0);
            }
        }

        if (use_mask) {
            #pragma unroll
            for (int f = 0; f < 2; ++f) {
                const long mrow = (long)(q0 + f*16 + l15) * S_LEN + kt*BK;
                #pragma unroll
                for (int nt = 0; nt < 4; ++nt)
                    #pragma unroll
                    for (int r = 0; r < 4; ++r)
                        st[f][nt][r] += mfac * mask[mrow + nt*16 + quad*4 + r];
            }
        }

        float alpha[2];
        #pragma unroll
        for (int f = 0; f < 2; ++f) {
            float mx = fmaxf(fmaxf(fmaxf(st[f][0][0], st[f][0][1]), fmaxf(st[f][0][2], st[f][0][3])),
                             fmaxf(fmaxf(st[f][1][0], st[f][1][1]), fmaxf(st[f][1][2], st[f][1][3])));
            float mx2 = fmaxf(fmaxf(fmaxf(st[f][2][0], st[f][2][1]), fmaxf(st[f][2][2], st[f][2][3])),
                              fmaxf(fmaxf(st[f][3][0], st[f][3][1]), fmaxf(st[f][3][2], st[f][3][3])));
            mx = fmaxf(mx, mx2);
            mx = fmaxf(mx, __shfl_xor(mx, 16, 64));
            mx = fmaxf(mx, __shfl_xor(mx, 32, 64));
            float mnew = fmaxf(m_i[f], mx);
            float rsum = 0.0f;
            #pragma unroll
            for (int nt = 0; nt < 4; ++nt) {
                #pragma unroll
                for (int r = 0; r < 4; ++r) {
                    float p = __builtin_amdgcn_exp2f(st[f][nt][r] - mnew);
                    st[f][nt][r] = p;
                    rsum += p;
                }
            }
            rsum += __shfl_xor(rsum, 16, 64);
            rsum += __shfl_xor(rsum, 32, 64);
            alpha[f] = __builtin_amdgcn_exp2f(m_i[f] - mnew);
            l_i[f] = alpha[f] * l_i[f] + rsum;
            m_i[f] = mnew;
        }

        #pragma unroll
        for (int f = 0; f < 2; ++f)
            #pragma unroll
            for (int r = 0; r < 4; ++r) {
                float a_r = __shfl(alpha[f], quad*4 + r, 64);
                #pragma unroll
                for (int dt = 0; dt < 4; ++dt) o[f][dt][r] *= a_r;
            }

        #pragma unroll
        for (int f = 0; f < 2; ++f)
            #pragma unroll
            for (int nt = 0; nt < 4; ++nt) {
                union { pk16x2 p[2]; half4v h; } up;
                up.p[0] = __builtin_amdgcn_cvt_pkrtz(st[f][nt][0], st[f][nt][1]);
                up.p[1] = __builtin_amdgcn_cvt_pkrtz(st[f][nt][2], st[f][nt][3]);
                *(half4v*)&Pw[wave][f*16 + l15][nt*16 + quad*4] = up.h;
            }

        #pragma unroll
        for (int kc2 = 0; kc2 < 2; ++kc2) {
            half8 pa0 = *(const half8*)&Pw[wave][l15][kc2*32 + quad*8];
            half8 pa1 = *(const half8*)&Pw[wave][16 + l15][kc2*32 + quad*8];
            #pragma unroll
            for (int dt = 0; dt < 4; ++dt) {
                const int row = dt*16 + l15;
                const int pb  = (4*kc2 + quad) ^ (row >> 3);
                half8 vb = *(const half8*)&Vt[b][row*KPAD + pb*8];
                o[0][dt] = __builtin_amdgcn_mfma_f32_16x16x32_f16(pa0, vb, o[0][dt], 0, 0, 0);
                o[1][dt] = __builtin_amdgcn_mfma_f32_16x16x32_f16(pa1, vb, o[1][dt], 0, 0, 0);
            }
        }

        if (kt + 1 < NT) {
            store_tile((kt + 1) & 1);
            __syncthreads();
        }
    }

    #pragma unroll
    for (int f = 0; f < 2; ++f) {
        #pragma unroll
        for (int r = 0; r < 4; ++r) {
            float lq = __shfl(l_i[f], quad*4 + r, 64);
            float linv = __builtin_amdgcn_rcpf(lq);
            const long row = (long)(q0 + f*16 + quad*4 + r) * DHEAD;
            #pragma unroll
            for (int dt = 0; dt < 4; ++dt)
                Oh[row + dt*16 + l15] = o[f][dt][r] * linv;
        }
    }
}

extern "C" void kernel_launch(void* const* d_in, const int* in_sizes, int n_in,
                              void* d_out, int out_size, void* d_ws, size_t ws_size,
                              hipStream_t stream) {
    const float* Q    = (const float*)d_in[0];
    const float* K    = (const float*)d_in[1];
    const float* V    = (const float*)d_in[2];
    const int*   dk   = (const int*)d_in[3];
    const float* mask = (const float*)d_in[4];
    float* out = (float*)d_out;
    int* flag = (int*)d_ws;

    (void)hipMemsetAsync(flag, 0, sizeof(int), stream);
    mask_flag_kernel<<<2048, 256, 0, stream>>>((const float4*)mask, flag);

    if (ws_size >= 256) {
        attn32f_kernel<<<512, 512, 0, stream>>>(Q, K, V, dk, mask, flag, out);
    } else {
        dim3 grid(S_LEN / BQ, NBH);
        attn_kernel_fb<<<grid, 256, 0, stream>>>(Q, K, V, dk, mask, flag, out);
    }
}

// Round 8
// 281.308 us; speedup vs baseline: 2.1565x; 2.1565x over previous
//
#include <hip/hip_runtime.h>

#define S_LEN 4096
#define DHEAD 64
#define BK    64       // K/V rows per tile
#define NT    (S_LEN / BK)
#define NBH   16
#define KPAD  72       // fp32 fallback kernel only
#define BQ    128      // fp32 fallback kernel only
#define TILE_HALFS (BK * DHEAD)   // 4096 halfs / floats per tile

typedef __fp16   pk16x2 __attribute__((ext_vector_type(2)));
typedef _Float16 half4v __attribute__((ext_vector_type(4)));
typedef _Float16 half8  __attribute__((ext_vector_type(8)));
typedef float    f32x4  __attribute__((ext_vector_type(4)));
typedef float    f32x16 __attribute__((ext_vector_type(16)));
typedef unsigned uint2v __attribute__((ext_vector_type(2)));

#define MFMA32(a, b, c) __builtin_amdgcn_mfma_f32_32x32x16_f16(a, b, c, 0, 0, 0)

__device__ __forceinline__ unsigned pk2u(float a, float b) {
    union { pk16x2 p; unsigned u; } x;
    x.p = __builtin_amdgcn_cvt_pkrtz(a, b);
    return x.u;
}

// permlane32_swap(x,y): r.x[l] = l<32 ? x[l] : y[l-32] ; r.y[l] = l<32 ? x[l+32] : y[l]
__device__ __forceinline__ uint2v pls(unsigned x, unsigned y) {
    return __builtin_amdgcn_permlane32_swap(x, y, false, false);
}
__device__ __forceinline__ float xmax32(float v) {
    uint2v r = pls(__float_as_uint(v), __float_as_uint(v));
    return fmaxf(__uint_as_float(r.x), __uint_as_float(r.y));
}
__device__ __forceinline__ float xadd32(float v) {
    uint2v r = pls(__float_as_uint(v), __float_as_uint(v));
    return __uint_as_float(r.x) + __uint_as_float(r.y);
}

// ---------------------------------------------------------------------------
// Mask scan: is the mask anywhere nonzero?
// ---------------------------------------------------------------------------
__global__ void mask_flag_kernel(const float4* __restrict__ mask, int* __restrict__ flag) {
    const long stride = 2048L * 256;
    long i = (long)blockIdx.x * 256 + threadIdx.x;
    int nz = 0;
    #pragma unroll
    for (int it = 0; it < 8; ++it) {
        float4 a = mask[i + it * stride];
        nz |= (a.x != 0.f) | (a.y != 0.f) | (a.z != 0.f) | (a.w != 0.f);
    }
    if (__any(nz)) {
        if ((threadIdx.x & 63) == 0) atomicOr(flag, 1);
    }
}

// ---------------------------------------------------------------------------
// Attention, ONE pass over fp32 K/V (no conv kernel): 512-thread blocks,
// in-block KV-split (waves 0-3 half A, 4-7 half B), inline fp32->fp16 staging
// into the swizzled LDS images, r3-verified 32x32 inner loop (pls-direct PV,
// THR=8 defer-max, VALU l-sums), in-LDS merge (no fences / atomics / combine).
// launch_bounds(512,2): 256-VGPR cap -- NO SPILL (r7's (512,4) capped at 128
// and spilled ~1.1 GB of scratch). store_tile placed right after QK^T: the
// staging registers die before softmax/PV, cutting peak pressure ~30 regs.
//   KT[r][chunk c] = K[r][8*(c ^ (r&7)) .. +8]
//   VT[d][chunk c] = V[8*(c ^ (d&7) ^ (d>>3 &7)) + j][d]
// ---------------------------------------------------------------------------
__global__ __launch_bounds__(512, 2) void attn32f_kernel(
    const float* __restrict__ Q, const float* __restrict__ K,
    const float* __restrict__ V, const int* __restrict__ dkp,
    const float* __restrict__ mask, const int* __restrict__ maskflag,
    float* __restrict__ O)
{
    const int bid = blockIdx.x;
    const int L   = (bid & 7) * 64 + (bid >> 3);   // XCD-contiguous decode
    const int bh  = L >> 5;
    const int qt  = L & 31;

    const int tid  = threadIdx.x;
    const int hf   = tid >> 8;          // KV half (0: kt 0..31, 1: kt 32..63)
    const int t    = tid & 255;         // tid within half
    const int w    = (tid >> 6) & 3;    // wave within half
    const int lane = tid & 63;
    const int l31  = lane & 31;
    const int h    = lane >> 5;
    const int cx   = lane & 7;                       // K read key
    const int vkey = (l31 ^ (l31 >> 3)) & 7;         // V read key (row l31)

    const int HT  = NT / 2;             // 32 tiles per half
    const int kt0 = hf * HT;

    const long gbase = (long)bh * S_LEN * DHEAD;
    const float* Qh = Q + gbase;
    const float* Kh = K + gbase;
    const float* Vh = V + gbase;

    const int q0 = qt * 128 + w * 32;
    const float csq  = rsqrtf((float)dkp[0]) * 1.44269504088896f;
    const float mfac = -1e9f * 1.44269504088896f;
    const bool use_mask = (maskflag[0] != 0);

    __shared__ __align__(16) _Float16 KT[2][2][TILE_HALFS];   // [hf][buf] 32 KB
    __shared__ __align__(16) _Float16 VT[2][2][TILE_HALFS];   // [hf][buf] 32 KB

    // ---- Q B-operand frags, pre-scaled ----
    half8 qf[4];
    #pragma unroll
    for (int ks = 0; ks < 4; ++ks) {
        const float4* src = (const float4*)(Qh + (long)(q0 + l31) * DHEAD + ks * 16 + h * 8);
        float4 a = src[0], b = src[1];
        union { unsigned u[4]; half8 h8; } u;
        u.u[0] = pk2u(a.x * csq, a.y * csq);
        u.u[1] = pk2u(a.z * csq, a.w * csq);
        u.u[2] = pk2u(b.x * csq, b.y * csq);
        u.u[3] = pk2u(b.z * csq, b.w * csq);
        qf[ks] = u.h8;
    }

    // ---- staging roles (within half) ----
    const int kr  = t >> 2;             // K row 0..63
    const int ks4 = t & 3;              // K 16-float segment
    const int vrp = t >> 3;             // V row-pair 0..31
    const int vdq = t & 7;              // V d-octet 0..7
    const float* Kb = Kh + (long)kr * DHEAD + ks4 * 16;
    const float* Vb = Vh + (long)(2 * vrp) * DHEAD + vdq * 8;
    const int kcol0 = (((2 * ks4)     ^ (kr & 7)) << 3);
    const int kcol1 = (((2 * ks4 + 1) ^ (kr & 7)) << 3);
    const int vd0   = vdq * 8;
    const int voct  = vrp >> 2;         // V row-octet
    const int vlow  = (2 * vrp) & 7;    // position within chunk

    float4 kf[4], vf[4];
    auto load_tile = [&](int kt) {
        const float4* kp  = (const float4*)(Kb + (long)kt * TILE_HALFS);
        kf[0] = kp[0]; kf[1] = kp[1]; kf[2] = kp[2]; kf[3] = kp[3];
        const float4* vp0 = (const float4*)(Vb + (long)kt * TILE_HALFS);
        const float4* vp1 = (const float4*)(Vb + (long)kt * TILE_HALFS + DHEAD);
        vf[0] = vp0[0]; vf[1] = vp0[1]; vf[2] = vp1[0]; vf[3] = vp1[1];
    };
    auto store_tile = [&](int bb) {
        union { unsigned u[4]; half8 h8; } u0, u1;
        u0.u[0] = pk2u(kf[0].x, kf[0].y);
        u0.u[1] = pk2u(kf[0].z, kf[0].w);
        u0.u[2] = pk2u(kf[1].x, kf[1].y);
        u0.u[3] = pk2u(kf[1].z, kf[1].w);
        u1.u[0] = pk2u(kf[2].x, kf[2].y);
        u1.u[1] = pk2u(kf[2].z, kf[2].w);
        u1.u[2] = pk2u(kf[3].x, kf[3].y);
        u1.u[3] = pk2u(kf[3].z, kf[3].w);
        *(half8*)&KT[hf][bb][kr * 64 + kcol0] = u0.h8;
        *(half8*)&KT[hf][bb][kr * 64 + kcol1] = u1.h8;
        _Float16* vt = &VT[hf][bb][0];
        #define VCOL(j) ((((voct ^ (j) ^ vdq) & 7) << 3) + vlow)
        *(pk16x2*)&vt[(vd0 + 0) * 64 + VCOL(0)] = __builtin_amdgcn_cvt_pkrtz(vf[0].x, vf[2].x);
        *(pk16x2*)&vt[(vd0 + 1) * 64 + VCOL(1)] = __builtin_amdgcn_cvt_pkrtz(vf[0].y, vf[2].y);
        *(pk16x2*)&vt[(vd0 + 2) * 64 + VCOL(2)] = __builtin_amdgcn_cvt_pkrtz(vf[0].z, vf[2].z);
        *(pk16x2*)&vt[(vd0 + 3) * 64 + VCOL(3)] = __builtin_amdgcn_cvt_pkrtz(vf[0].w, vf[2].w);
        *(pk16x2*)&vt[(vd0 + 4) * 64 + VCOL(4)] = __builtin_amdgcn_cvt_pkrtz(vf[1].x, vf[3].x);
        *(pk16x2*)&vt[(vd0 + 5) * 64 + VCOL(5)] = __builtin_amdgcn_cvt_pkrtz(vf[1].y, vf[3].y);
        *(pk16x2*)&vt[(vd0 + 6) * 64 + VCOL(6)] = __builtin_amdgcn_cvt_pkrtz(vf[1].z, vf[3].z);
        *(pk16x2*)&vt[(vd0 + 7) * 64 + VCOL(7)] = __builtin_amdgcn_cvt_pkrtz(vf[1].w, vf[3].w);
        #undef VCOL
    };

    f32x16 o0 = {0.f,0.f,0.f,0.f,0.f,0.f,0.f,0.f,0.f,0.f,0.f,0.f,0.f,0.f,0.f,0.f};
    f32x16 o1 = o0;
    float m_i = -INFINITY;
    float l_i = 0.0f;

    load_tile(kt0);
    store_tile(0);
    __syncthreads();

    for (int lt = 0; lt < HT; ++lt) {
        const int kt = kt0 + lt;
        const int b  = lt & 1;
        if (lt + 1 < HT) load_tile(kt + 1);   // issue global prefetch

        // ---- S^T = K . Q^T ----
        f32x16 s0 = {0.f,0.f,0.f,0.f,0.f,0.f,0.f,0.f,0.f,0.f,0.f,0.f,0.f,0.f,0.f,0.f};
        f32x16 s1 = s0;
        __builtin_amdgcn_s_setprio(1);
        #pragma unroll
        for (int ks = 0; ks < 4; ++ks) {
            const int off = (((2 * ks + h) ^ cx) << 3);
            half8 a0 = *(const half8*)&KT[hf][b][(l31 << 6) + off];
            half8 a1 = *(const half8*)&KT[hf][b][2048 + (l31 << 6) + off];
            s0 = MFMA32(a0, qf[ks], s0);
            s1 = MFMA32(a1, qf[ks], s1);
        }
        __builtin_amdgcn_s_setprio(0);

        // ---- stage next tile NOW: staging regs die before softmax/PV.
        // Safe: writes touch only buffer b^1, which no wave reads during lt
        // (prev readers are behind the lt-1 barrier); barrier below publishes.
        if (lt + 1 < HT) store_tile(b ^ 1);

        if (use_mask) {
            const float* mrow = mask + (long)(q0 + l31) * S_LEN + kt * BK;
            #pragma unroll
            for (int r = 0; r < 16; ++r) {
                const int k = (r & 3) + ((r >> 2) << 3) + (h << 2);
                s0[r] += mfac * mrow[k];
                s1[r] += mfac * mrow[32 + k];
            }
        }

        // ---- online softmax, THR=8 defer-max ----
        {
            float tt[8];
            #pragma unroll
            for (int i = 0; i < 8; ++i)
                tt[i] = fmaxf(fmaxf(s0[2*i], s0[2*i+1]), fmaxf(s1[2*i], s1[2*i+1]));
            float mx = fmaxf(fmaxf(fmaxf(tt[0], tt[1]), fmaxf(tt[2], tt[3])),
                             fmaxf(fmaxf(tt[4], tt[5]), fmaxf(tt[6], tt[7])));
            mx = xmax32(mx);
            const bool need = __any(mx > m_i + 8.0f);
            const float mnew = need ? fmaxf(m_i, mx) : m_i;
            float ra = 0.f, rb = 0.f;
            #pragma unroll
            for (int r = 0; r < 16; ++r) {
                float p0 = __builtin_amdgcn_exp2f(s0[r] - mnew);
                float p1 = __builtin_amdgcn_exp2f(s1[r] - mnew);
                s0[r] = p0; s1[r] = p1;
                ra += p0; rb += p1;
            }
            float rsum = xadd32(ra + rb);
            if (need) {
                const float alpha = __builtin_amdgcn_exp2f(m_i - mnew);
                #pragma unroll
                for (int r = 0; r < 16; ++r) {
                    const int qr = (r & 3) + ((r >> 2) << 3) + (h << 2);
                    float a_r = __shfl(alpha, qr, 64);
                    o0[r] *= a_r; o1[r] *= a_r;
                }
                l_i = alpha * l_i + rsum;
                m_i = mnew;
            } else {
                l_i += rsum;
            }
        }

        // ---- P words -> PV A-operand via direct pls ----
        unsigned wp[16];
        #pragma unroll
        for (int d = 0; d < 8; ++d) {
            wp[d]     = pk2u(s0[2*d], s0[2*d+1]);
            wp[8 + d] = pk2u(s1[2*d], s1[2*d+1]);
        }

        __builtin_amdgcn_s_setprio(1);
        #pragma unroll
        for (int si = 0; si < 4; ++si) {
            const int bs = (si >> 1) * 8 + (si & 1) * 4;
            uint2v r0 = pls(wp[bs + 0], wp[bs + 2]);
            uint2v r1 = pls(wp[bs + 1], wp[bs + 3]);
            union { unsigned u[4]; half8 h8; } pa;
            pa.u[0] = r0.x; pa.u[1] = r1.x; pa.u[2] = r0.y; pa.u[3] = r1.y;
            const int voff = (((2 * si + h) ^ vkey) << 3);
            half8 v0 = *(const half8*)&VT[hf][b][(l31 << 6) + voff];
            half8 v1 = *(const half8*)&VT[hf][b][2048 + (l31 << 6) + (voff ^ 32)];
            o0 = MFMA32(pa.h8, v0, o0);
            o1 = MFMA32(pa.h8, v1, o1);
        }
        __builtin_amdgcn_s_setprio(0);

        if (lt + 1 < HT) __syncthreads();    // publish b^1 for next iteration
    }

    // ---- in-block merge of the two halves (LDS + __syncthreads only) ----
    float*  comb = (float*)&KT[0][0][0];     // [w][row 0..31][col 0..63] = 32 KB
    float2* mlA  = (float2*)&VT[0][0][0];    // half A (m,l): [w*32+row]
    float2* mlB  = mlA + 128;                // half B (m,l)

    __syncthreads();                          // all tile compute done
    if (hf == 1) {
        #pragma unroll
        for (int r = 0; r < 16; ++r) {
            const int qr = (r & 3) + ((r >> 2) << 3) + (h << 2);
            comb[w * 2048 + qr * 64 + l31]      = o0[r];
            comb[w * 2048 + qr * 64 + 32 + l31] = o1[r];
        }
        if (h == 0) mlB[w * 32 + l31] = make_float2(m_i, l_i);
    } else {
        if (h == 0) mlA[w * 32 + l31] = make_float2(m_i, l_i);
    }
    __syncthreads();

    if (hf == 0) {
        float* dst = O + gbase;
        #pragma unroll
        for (int r = 0; r < 16; ++r) {
            const int qr = (r & 3) + ((r >> 2) << 3) + (h << 2);
            const float2 ml1 = mlA[w * 32 + qr];
            const float2 ml2 = mlB[w * 32 + qr];
            const float m   = fmaxf(ml1.x, ml2.x);
            const float a1  = __builtin_amdgcn_exp2f(ml1.x - m);
            const float a2  = __builtin_amdgcn_exp2f(ml2.x - m);
            const float inv = __builtin_amdgcn_rcpf(ml1.y * a1 + ml2.y * a2);
            const float p0  = comb[w * 2048 + qr * 64 + l31];
            const float p1  = comb[w * 2048 + qr * 64 + 32 + l31];
            const long row = (long)(q0 + qr) * DHEAD;
            dst[row + l31]      = (o0[r] * a1 + p0 * a2) * inv;
            dst[row + 32 + l31] = (o1[r] * a1 + p1 * a2) * inv;
        }
    }
}

// ---------------------------------------------------------------------------
// Tiny-ws fallback: verified fp32-input kernel, verbatim.
// ---------------------------------------------------------------------------
__global__ __launch_bounds__(256, 2) void attn_kernel_fb(
    const float* __restrict__ Q, const float* __restrict__ K,
    const float* __restrict__ V, const int* __restrict__ dk,
    const float* __restrict__ mask, const int* __restrict__ maskflag,
    float* __restrict__ O)
{
    const int qt   = blockIdx.x;
    const int bh   = blockIdx.y;
    const int tid  = threadIdx.x;
    const int wave = tid >> 6;
    const int lane = tid & 63;
    const int l15  = lane & 15;
    const int quad = lane >> 4;

    const long base = (long)bh * S_LEN * DHEAD;
    const float* Qh = Q + base;
    const float* Kh = K + base;
    const float* Vh = V + base;
    float*       Oh = O + base;

    const int q0 = qt * BQ + wave * 32;
    const float csq  = rsqrtf((float)dk[0]) * 1.44269504088896f;
    const float mfac = -1e9f * 1.44269504088896f;
    const bool use_mask = (maskflag[0] != 0);

    __shared__ __align__(16) _Float16 Kt[2][BK][KPAD];
    __shared__ __align__(16) _Float16 Vt[2][DHEAD * KPAD];
    __shared__ __align__(16) _Float16 Pw[4][32][KPAD];

    half8 qf[2][2];
    #pragma unroll
    for (int f = 0; f < 2; ++f) {
        #pragma unroll
        for (int kc = 0; kc < 2; ++kc) {
            const float4* src = (const float4*)(Qh + (long)(q0 + f*16 + l15) * DHEAD + kc*32 + quad*8);
            float4 a = src[0], b = src[1];
            union { pk16x2 p[4]; half8 h; } u;
            u.p[0] = __builtin_amdgcn_cvt_pkrtz(a.x*csq, a.y*csq);
            u.p[1] = __builtin_amdgcn_cvt_pkrtz(a.z*csq, a.w*csq);
            u.p[2] = __builtin_amdgcn_cvt_pkrtz(b.x*csq, b.y*csq);
            u.p[3] = __builtin_amdgcn_cvt_pkrtz(b.z*csq, b.w*csq);
            qf[f][kc] = u.h;
        }
    }

    const int kr  = tid >> 2;
    const int ks  = tid & 3;
    const int vrp = tid >> 3;
    const int vdq = tid & 7;
    const float* Kb = Kh + (long)kr * DHEAD + ks * 16;
    const float* Vb = Vh + (long)(2 * vrp) * DHEAD + vdq * 8;
    const int vcol = (((vrp >> 2) ^ vdq) << 3) + ((2 * vrp) & 7);
    const int vd0  = vdq * 8;

    float4 kf[4], vf[4];
    auto load_tile = [&](int kt) {
        const float4* kp  = (const float4*)(Kb + (long)kt * BK * DHEAD);
        kf[0] = kp[0]; kf[1] = kp[1]; kf[2] = kp[2]; kf[3] = kp[3];
        const float4* vp0 = (const float4*)(Vb + (long)kt * BK * DHEAD);
        const float4* vp1 = (const float4*)(Vb + (long)kt * BK * DHEAD + DHEAD);
        vf[0] = vp0[0]; vf[1] = vp0[1]; vf[2] = vp1[0]; vf[3] = vp1[1];
    };
    auto store_tile = [&](int b) {
        union { pk16x2 p[4]; half8 h; } u0, u1;
        u0.p[0] = __builtin_amdgcn_cvt_pkrtz(kf[0].x, kf[0].y);
        u0.p[1] = __builtin_amdgcn_cvt_pkrtz(kf[0].z, kf[0].w);
        u0.p[2] = __builtin_amdgcn_cvt_pkrtz(kf[1].x, kf[1].y);
        u0.p[3] = __builtin_amdgcn_cvt_pkrtz(kf[1].z, kf[1].w);
        u1.p[0] = __builtin_amdgcn_cvt_pkrtz(kf[2].x, kf[2].y);
        u1.p[1] = __builtin_amdgcn_cvt_pkrtz(kf[2].z, kf[2].w);
        u1.p[2] = __builtin_amdgcn_cvt_pkrtz(kf[3].x, kf[3].y);
        u1.p[3] = __builtin_amdgcn_cvt_pkrtz(kf[3].z, kf[3].w);
        *(half8*)&Kt[b][kr][ks*16]     = u0.h;
        *(half8*)&Kt[b][kr][ks*16 + 8] = u1.h;
        _Float16* vt = &Vt[b][0];
        *(pk16x2*)&vt[(vd0+0)*KPAD + vcol] = __builtin_amdgcn_cvt_pkrtz(vf[0].x, vf[2].x);
        *(pk16x2*)&vt[(vd0+1)*KPAD + vcol] = __builtin_amdgcn_cvt_pkrtz(vf[0].y, vf[2].y);
        *(pk16x2*)&vt[(vd0+2)*KPAD + vcol] = __builtin_amdgcn_cvt_pkrtz(vf[0].z, vf[2].z);
        *(pk16x2*)&vt[(vd0+3)*KPAD + vcol] = __builtin_amdgcn_cvt_pkrtz(vf[0].w, vf[2].w);
        *(pk16x2*)&vt[(vd0+4)*KPAD + vcol] = __builtin_amdgcn_cvt_pkrtz(vf[1].x, vf[3].x);
        *(pk16x2*)&vt[(vd0+5)*KPAD + vcol] = __builtin_amdgcn_cvt_pkrtz(vf[1].y, vf[3].y);
        *(pk16x2*)&vt[(vd0+6)*KPAD + vcol] = __builtin_amdgcn_cvt_pkrtz(vf[1].z, vf[3].z);
        *(pk16x2*)&vt[(vd0+7)*KPAD + vcol] = __builtin_amdgcn_cvt_pkrtz(vf[1].w, vf[3].w);
    };

    f32x4 o[2][4];
    #pragma unroll
    for (int f = 0; f < 2; ++f)
        #pragma unroll
        for (int dt = 0; dt < 4; ++dt) o[f][dt] = (f32x4){0.f, 0.f, 0.f, 0.f};
    float m_i[2] = {-INFINITY, -INFINITY};
    float l_i[2] = {0.0f, 0.0f};

    load_tile(0);
    store_tile(0);
    __syncthreads();

    for (int kt = 0; kt < NT; ++kt) {
        const int b = kt & 1;
        if (kt + 1 < NT) load_tile(kt + 1);

        f32x4 st[2][4];
        #pragma unroll
        for (int f = 0; f < 2; ++f)
            #pragma unroll
            for (int nt = 0; nt < 4; ++nt) st[f][nt] = (f32x4){0.f,0.f,0.f,0.f};
        #pragma unroll
        for (int nt = 0; nt < 4; ++nt) {
            #pragma unroll
            for (int kc = 0; kc < 2; ++kc) {
                half8 af = *(const half8*)&Kt[b][nt*16 + l15][kc*32 + quad*8];
                st[0][nt] = __builtin_amdgcn_mfma_f32_16x16x32_f16(af, qf[0][kc], st[0][nt], 0, 0, 0);
                st[1][nt] = __builtin_amdgcn_mfma_f32_16x16x32_f16(af, qf[1][kc], st[1][nt], 0, 0, 0);
            }
        }

        if (use_mask) {
            #pragma unroll
            for (int f = 0; f < 2; ++f) {
                const long mrow = (long)(q0 + f*16 + l15) * S_LEN + kt*BK;
                #pragma unroll
                for (int nt = 0; nt < 4; ++nt)
                    #pragma unroll
                    for (int r = 0; r < 4; ++r)
                        st[f][nt][r] += mfac * mask[mrow + nt*16 + quad*4 + r];
            }
        }

        float alpha[2];
        #pragma unroll
        for (int f = 0; f < 2; ++f) {
            float mx = fmaxf(fmaxf(fmaxf(st[f][0][0], st[f][0][1]), fmaxf(st[f][0][2], st[f][0][3])),
                             fmaxf(fmaxf(st[f][1][0], st[f][1][1]), fmaxf(st[f][1][2], st[f][1][3])));
            float mx2 = fmaxf(fmaxf(fmaxf(st[f][2][0], st[f][2][1]), fmaxf(st[f][2][2], st[f][2][3])),
                              fmaxf(fmaxf(st[f][3][0], st[f][3][1]), fmaxf(st[f][3][2], st[f][3][3])));
            mx = fmaxf(mx, mx2);
            mx = fmaxf(mx, __shfl_xor(mx, 16, 64));
            mx = fmaxf(mx, __shfl_xor(mx, 32, 64));
            float mnew = fmaxf(m_i[f], mx);
            float rsum = 0.0f;
            #pragma unroll
            for (int nt = 0; nt < 4; ++nt) {
                #pragma unroll
                for (int r = 0; r < 4; ++r) {
                    float p = __builtin_amdgcn_exp2f(st[f][nt][r] - mnew);
                    st[f][nt][r] = p;
                    rsum += p;
                }
            }
            rsum += __shfl_xor(rsum, 16, 64);
            rsum += __shfl_xor(rsum, 32, 64);
            alpha[f] = __builtin_amdgcn_exp2f(m_i[f] - mnew);
            l_i[f] = alpha[f] * l_i[f] + rsum;
            m_i[f] = mnew;
        }

        #pragma unroll
        for (int f = 0; f < 2; ++f)
            #pragma unroll
            for (int r = 0; r < 4; ++r) {
                float a_r = __shfl(alpha[f], quad*4 + r, 64);
                #pragma unroll
                for (int dt = 0; dt < 4; ++dt) o[f][dt][r] *= a_r;
            }

        #pragma unroll
        for (int f = 0; f < 2; ++f)
            #pragma unroll
            for (int nt = 0; nt < 4; ++nt) {
                union { pk16x2 p[2]; half4v h; } up;
                up.p[0] = __builtin_amdgcn_cvt_pkrtz(st[f][nt][0], st[f][nt][1]);
                up.p[1] = __builtin_amdgcn_cvt_pkrtz(st[f][nt][2], st[f][nt][3]);
                *(half4v*)&Pw[wave][f*16 + l15][nt*16 + quad*4] = up.h;
            }

        #pragma unroll
        for (int kc2 = 0; kc2 < 2; ++kc2) {
            half8 pa0 = *(const half8*)&Pw[wave][l15][kc2*32 + quad*8];
            half8 pa1 = *(const half8*)&Pw[wave][16 + l15][kc2*32 + quad*8];
            #pragma unroll
            for (int dt = 0; dt < 4; ++dt) {
                const int row = dt*16 + l15;
                const int pb  = (4*kc2 + quad) ^ (row >> 3);
                half8 vb = *(const half8*)&Vt[b][row*KPAD + pb*8];
                o[0][dt] = __builtin_amdgcn_mfma_f32_16x16x32_f16(pa0, vb, o[0][dt], 0, 0, 0);
                o[1][dt] = __builtin_amdgcn_mfma_f32_16x16x32_f16(pa1, vb, o[1][dt], 0, 0, 0);
            }
        }

        if (kt + 1 < NT) {
            store_tile((kt + 1) & 1);
            __syncthreads();
        }
    }

    #pragma unroll
    for (int f = 0; f < 2; ++f) {
        #pragma unroll
        for (int r = 0; r < 4; ++r) {
            float lq = __shfl(l_i[f], quad*4 + r, 64);
            float linv = __builtin_amdgcn_rcpf(lq);
            const long row = (long)(q0 + f*16 + quad*4 + r) * DHEAD;
            #pragma unroll
            for (int dt = 0; dt < 4; ++dt)
                Oh[row + dt*16 + l15] = o[f][dt][r] * linv;
        }
    }
}

extern "C" void kernel_launch(void* const* d_in, const int* in_sizes, int n_in,
                              void* d_out, int out_size, void* d_ws, size_t ws_size,
                              hipStream_t stream) {
    const float* Q    = (const float*)d_in[0];
    const float* K    = (const float*)d_in[1];
    const float* V    = (const float*)d_in[2];
    const int*   dk   = (const int*)d_in[3];
    const float* mask = (const float*)d_in[4];
    float* out = (float*)d_out;
    int* flag = (int*)d_ws;

    (void)hipMemsetAsync(flag, 0, sizeof(int), stream);
    mask_flag_kernel<<<2048, 256, 0, stream>>>((const float4*)mask, flag);

    if (ws_size >= 256) {
        attn32f_kernel<<<512, 512, 0, stream>>>(Q, K, V, dk, mask, flag, out);
    } else {
        dim3 grid(S_LEN / BQ, NBH);
        attn_kernel_fb<<<grid, 256, 0, stream>>>(Q, K, V, dk, mask, flag, out);
    }
}

// Round 9
// 248.351 us; speedup vs baseline: 2.4427x; 1.1327x over previous
//
#include <hip/hip_runtime.h>

#define S_LEN 4096
#define DHEAD 64
#define BQ    128      // Q rows per block (4 waves x 32)
#define BK    64       // K/V rows per tile
#define NT    (S_LEN / BK)
#define KPAD  72       // halfs; 144 B row stride (16B-aligned)

typedef __fp16   pk16x2 __attribute__((ext_vector_type(2)));  // cvt_pkrtz result
typedef _Float16 half4v __attribute__((ext_vector_type(4)));
typedef _Float16 half8  __attribute__((ext_vector_type(8)));
typedef float    f32x4  __attribute__((ext_vector_type(4)));
typedef unsigned uint2v __attribute__((ext_vector_type(2)));

// permlane32_swap(x,y): r.x[l] = l<32 ? x[l] : y[l-32] ; r.y[l] = l<32 ? x[l+32] : y[l]
__device__ __forceinline__ uint2v pls(unsigned x, unsigned y) {
    return __builtin_amdgcn_permlane32_swap(x, y, false, false);
}
// VALU equivalents of (v OP shfl_xor(v,32)) -- no DS op on the serial chain
__device__ __forceinline__ float xmax32(float v) {
    uint2v r = pls(__float_as_uint(v), __float_as_uint(v));
    return fmaxf(__uint_as_float(r.x), __uint_as_float(r.y));
}
__device__ __forceinline__ float xadd32(float v) {
    uint2v r = pls(__float_as_uint(v), __float_as_uint(v));
    return __uint_as_float(r.x) + __uint_as_float(r.y);
}

// ---------------------------------------------------------------------------
// Pass 1: is the mask anywhere nonzero? 2048x256 threads, 8 float4/thread.
// ---------------------------------------------------------------------------
__global__ void mask_flag_kernel(const float4* __restrict__ mask, int* __restrict__ flag) {
    const long stride = 2048L * 256;
    long i = (long)blockIdx.x * 256 + threadIdx.x;
    int nz = 0;
    #pragma unroll
    for (int it = 0; it < 8; ++it) {
        float4 a = mask[i + it * stride];
        nz |= (a.x != 0.f) | (a.y != 0.f) | (a.z != 0.f) | (a.w != 0.f);
    }
    if (__any(nz)) {
        if ((threadIdx.x & 63) == 0) atomicOr(flag, 1);
    }
}

// ---------------------------------------------------------------------------
// Pass 2: flash attention (r0 champion structure: 256 thr, WQ=32, 2 blocks/CU,
// inline fp32 staging, LDS double buffer, one barrier per K-tile) with three
// serial-chain cuts: THR=8 defer-max, s_setprio around MFMA clusters, and
// permlane32_swap replacing the xor-32 DS shuffles in the reductions.
// ---------------------------------------------------------------------------
__global__ __launch_bounds__(256, 2) void attn_kernel(
    const float* __restrict__ Q, const float* __restrict__ K,
    const float* __restrict__ V, const int* __restrict__ dk,
    const float* __restrict__ mask, const int* __restrict__ maskflag,
    float* __restrict__ O)
{
    const int qt   = blockIdx.x;      // 0..31
    const int bh   = blockIdx.y;      // 0..15
    const int tid  = threadIdx.x;
    const int wave = tid >> 6;
    const int lane = tid & 63;
    const int l15  = lane & 15;
    const int quad = lane >> 4;

    const long base = (long)bh * S_LEN * DHEAD;
    const float* Qh = Q + base;
    const float* Kh = K + base;
    const float* Vh = V + base;
    float*       Oh = O + base;

    const int q0 = qt * BQ + wave * 32;            // this wave's 32 q-rows
    const float csq  = rsqrtf((float)dk[0]) * 1.44269504088896f; // scale*log2(e)
    const float mfac = -1e9f * 1.44269504088896f;                // exp2 domain
    const bool use_mask = (maskflag[0] != 0);

    __shared__ __align__(16) _Float16 Kt[2][BK][KPAD];      // [buf][k-row][d]
    __shared__ __align__(16) _Float16 Vt[2][DHEAD * KPAD];  // [buf][d][r] swizzled
    __shared__ __align__(16) _Float16 Pw[4][32][KPAD];      // per-wave P: [q][k]

    // ---- Q fragments (B-operand layout), pre-scaled; 2 frags of 16 rows ----
    half8 qf[2][2];
    #pragma unroll
    for (int f = 0; f < 2; ++f) {
        #pragma unroll
        for (int kc = 0; kc < 2; ++kc) {
            const float4* src = (const float4*)(Qh + (long)(q0 + f*16 + l15) * DHEAD + kc*32 + quad*8);
            float4 a = src[0], b = src[1];
            union { pk16x2 p[4]; half8 h; } u;
            u.p[0] = __builtin_amdgcn_cvt_pkrtz(a.x*csq, a.y*csq);
            u.p[1] = __builtin_amdgcn_cvt_pkrtz(a.z*csq, a.w*csq);
            u.p[2] = __builtin_amdgcn_cvt_pkrtz(b.x*csq, b.y*csq);
            u.p[3] = __builtin_amdgcn_cvt_pkrtz(b.z*csq, b.w*csq);
            qf[f][kc] = u.h;
        }
    }

    // ---- staging roles + prefetch registers ----
    const int kr  = tid >> 2;            // K: row 0..63
    const int ks  = tid & 3;             // K: 16-float segment
    const int vrp = tid >> 3;            // V: row-pair 0..31
    const int vdq = tid & 7;             // V: d-octet 0..7
    const float* Kb = Kh + (long)kr * DHEAD + ks * 16;
    const float* Vb = Vh + (long)(2 * vrp) * DHEAD + vdq * 8;
    const int vcol = (((vrp >> 2) ^ vdq) << 3) + ((2 * vrp) & 7);  // swizzled col
    const int vd0  = vdq * 8;

    float4 kf[4], vf[4];
    auto load_tile = [&](int kt) {
        const float4* kp  = (const float4*)(Kb + (long)kt * BK * DHEAD);
        kf[0] = kp[0]; kf[1] = kp[1]; kf[2] = kp[2]; kf[3] = kp[3];
        const float4* vp0 = (const float4*)(Vb + (long)kt * BK * DHEAD);
        const float4* vp1 = (const float4*)(Vb + (long)kt * BK * DHEAD + DHEAD);
        vf[0] = vp0[0]; vf[1] = vp0[1]; vf[2] = vp1[0]; vf[3] = vp1[1];
    };
    auto store_tile = [&](int b) {
        union { pk16x2 p[4]; half8 h; } u0, u1;
        u0.p[0] = __builtin_amdgcn_cvt_pkrtz(kf[0].x, kf[0].y);
        u0.p[1] = __builtin_amdgcn_cvt_pkrtz(kf[0].z, kf[0].w);
        u0.p[2] = __builtin_amdgcn_cvt_pkrtz(kf[1].x, kf[1].y);
        u0.p[3] = __builtin_amdgcn_cvt_pkrtz(kf[1].z, kf[1].w);
        u1.p[0] = __builtin_amdgcn_cvt_pkrtz(kf[2].x, kf[2].y);
        u1.p[1] = __builtin_amdgcn_cvt_pkrtz(kf[2].z, kf[2].w);
        u1.p[2] = __builtin_amdgcn_cvt_pkrtz(kf[3].x, kf[3].y);
        u1.p[3] = __builtin_amdgcn_cvt_pkrtz(kf[3].z, kf[3].w);
        *(half8*)&Kt[b][kr][ks*16]     = u0.h;
        *(half8*)&Kt[b][kr][ks*16 + 8] = u1.h;
        _Float16* vt = &Vt[b][0];
        *(pk16x2*)&vt[(vd0+0)*KPAD + vcol] = __builtin_amdgcn_cvt_pkrtz(vf[0].x, vf[2].x);
        *(pk16x2*)&vt[(vd0+1)*KPAD + vcol] = __builtin_amdgcn_cvt_pkrtz(vf[0].y, vf[2].y);
        *(pk16x2*)&vt[(vd0+2)*KPAD + vcol] = __builtin_amdgcn_cvt_pkrtz(vf[0].z, vf[2].z);
        *(pk16x2*)&vt[(vd0+3)*KPAD + vcol] = __builtin_amdgcn_cvt_pkrtz(vf[0].w, vf[2].w);
        *(pk16x2*)&vt[(vd0+4)*KPAD + vcol] = __builtin_amdgcn_cvt_pkrtz(vf[1].x, vf[3].x);
        *(pk16x2*)&vt[(vd0+5)*KPAD + vcol] = __builtin_amdgcn_cvt_pkrtz(vf[1].y, vf[3].y);
        *(pk16x2*)&vt[(vd0+6)*KPAD + vcol] = __builtin_amdgcn_cvt_pkrtz(vf[1].z, vf[3].z);
        *(pk16x2*)&vt[(vd0+7)*KPAD + vcol] = __builtin_amdgcn_cvt_pkrtz(vf[1].w, vf[3].w);
    };

    f32x4 o[2][4];
    #pragma unroll
    for (int f = 0; f < 2; ++f)
        #pragma unroll
        for (int dt = 0; dt < 4; ++dt) o[f][dt] = (f32x4){0.f, 0.f, 0.f, 0.f};
    float m_i[2] = {-INFINITY, -INFINITY};
    float l_i[2] = {0.0f, 0.0f};

    load_tile(0);
    store_tile(0);
    __syncthreads();

    for (int kt = 0; kt < NT; ++kt) {
        const int b = kt & 1;
        if (kt + 1 < NT) load_tile(kt + 1);    // global prefetch overlaps compute

        // ---- S^T = K · Q^T for both frags (K-frag reads shared) ----
        f32x4 st[2][4];
        #pragma unroll
        for (int f = 0; f < 2; ++f)
            #pragma unroll
            for (int nt = 0; nt < 4; ++nt) st[f][nt] = (f32x4){0.f,0.f,0.f,0.f};
        __builtin_amdgcn_s_setprio(1);
        #pragma unroll
        for (int nt = 0; nt < 4; ++nt) {
            #pragma unroll
            for (int kc = 0; kc < 2; ++kc) {
                half8 af = *(const half8*)&Kt[b][nt*16 + l15][kc*32 + quad*8];
                st[0][nt] = __builtin_amdgcn_mfma_f32_16x16x32_f16(af, qf[0][kc], st[0][nt], 0, 0, 0);
                st[1][nt] = __builtin_amdgcn_mfma_f32_16x16x32_f16(af, qf[1][kc], st[1][nt], 0, 0, 0);
            }
        }
        __builtin_amdgcn_s_setprio(0);

        if (use_mask) {
            #pragma unroll
            for (int f = 0; f < 2; ++f) {
                const long mrow = (long)(q0 + f*16 + l15) * S_LEN + kt*BK;
                #pragma unroll
                for (int nt = 0; nt < 4; ++nt)
                    #pragma unroll
                    for (int r = 0; r < 4; ++r)
                        st[f][nt][r] += mfac * mask[mrow + nt*16 + quad*4 + r];
            }
        }

        // ---- online softmax (exp2 domain), THR=8 defer-max, per frag ----
        #pragma unroll
        for (int f = 0; f < 2; ++f) {
            float mx = fmaxf(fmaxf(fmaxf(st[f][0][0], st[f][0][1]), fmaxf(st[f][0][2], st[f][0][3])),
                             fmaxf(fmaxf(st[f][1][0], st[f][1][1]), fmaxf(st[f][1][2], st[f][1][3])));
            float mx2 = fmaxf(fmaxf(fmaxf(st[f][2][0], st[f][2][1]), fmaxf(st[f][2][2], st[f][2][3])),
                              fmaxf(fmaxf(st[f][3][0], st[f][3][1]), fmaxf(st[f][3][2], st[f][3][3])));
            mx = fmaxf(mx, mx2);
            mx = fmaxf(mx, __shfl_xor(mx, 16, 64));
            mx = xmax32(mx);                               // VALU, not DS
            const bool need = __any(mx > m_i[f] + 8.0f);   // wave-uniform
            const float mnew = need ? fmaxf(m_i[f], mx) : m_i[f];
            float rsum = 0.0f;
            #pragma unroll
            for (int nt = 0; nt < 4; ++nt) {
                #pragma unroll
                for (int r = 0; r < 4; ++r) {
                    float p = __builtin_amdgcn_exp2f(st[f][nt][r] - mnew);
                    st[f][nt][r] = p;
                    rsum += p;
                }
            }
            rsum += __shfl_xor(rsum, 16, 64);
            rsum = xadd32(rsum);                           // VALU, not DS
            if (need) {
                const float alpha = __builtin_amdgcn_exp2f(m_i[f] - mnew);
                #pragma unroll
                for (int r = 0; r < 4; ++r) {
                    float a_r = __shfl(alpha, quad*4 + r, 64);
                    #pragma unroll
                    for (int dt = 0; dt < 4; ++dt) o[f][dt][r] *= a_r;
                }
                l_i[f] = alpha * l_i[f] + rsum;
                m_i[f] = mnew;
            } else {
                l_i[f] += rsum;
            }
        }

        // ---- P -> per-wave LDS (b64 writes) ----
        #pragma unroll
        for (int f = 0; f < 2; ++f)
            #pragma unroll
            for (int nt = 0; nt < 4; ++nt) {
                union { pk16x2 p[2]; half4v h; } up;
                up.p[0] = __builtin_amdgcn_cvt_pkrtz(st[f][nt][0], st[f][nt][1]);
                up.p[1] = __builtin_amdgcn_cvt_pkrtz(st[f][nt][2], st[f][nt][3]);
                *(half4v*)&Pw[wave][f*16 + l15][nt*16 + quad*4] = up.h;
            }

        // ---- O += P·V  (V-frag reads shared across frags) ----
        __builtin_amdgcn_s_setprio(1);
        #pragma unroll
        for (int kc2 = 0; kc2 < 2; ++kc2) {
            half8 pa0 = *(const half8*)&Pw[wave][l15][kc2*32 + quad*8];
            half8 pa1 = *(const half8*)&Pw[wave][16 + l15][kc2*32 + quad*8];
            #pragma unroll
            for (int dt = 0; dt < 4; ++dt) {
                const int row = dt*16 + l15;
                const int pb  = (4*kc2 + quad) ^ (row >> 3);
                half8 vb = *(const half8*)&Vt[b][row*KPAD + pb*8];
                o[0][dt] = __builtin_amdgcn_mfma_f32_16x16x32_f16(pa0, vb, o[0][dt], 0, 0, 0);
                o[1][dt] = __builtin_amdgcn_mfma_f32_16x16x32_f16(pa1, vb, o[1][dt], 0, 0, 0);
            }
        }
        __builtin_amdgcn_s_setprio(0);

        if (kt + 1 < NT) {
            store_tile((kt + 1) & 1);   // other buffer; no read hazard
            __syncthreads();            // one barrier per K-tile
        }
    }

    // ---- epilogue: O /= l ----
    #pragma unroll
    for (int f = 0; f < 2; ++f) {
        #pragma unroll
        for (int r = 0; r < 4; ++r) {
            float lq = __shfl(l_i[f], quad*4 + r, 64);
            float linv = __builtin_amdgcn_rcpf(lq);
            const long row = (long)(q0 + f*16 + quad*4 + r) * DHEAD;
            #pragma unroll
            for (int dt = 0; dt < 4; ++dt)
                Oh[row + dt*16 + l15] = o[f][dt][r] * linv;
        }
    }
}

extern "C" void kernel_launch(void* const* d_in, const int* in_sizes, int n_in,
                              void* d_out, int out_size, void* d_ws, size_t ws_size,
                              hipStream_t stream) {
    const float* Q    = (const float*)d_in[0];
    const float* K    = (const float*)d_in[1];
    const float* V    = (const float*)d_in[2];
    const int*   dk   = (const int*)d_in[3];
    const float* mask = (const float*)d_in[4];
    float* out = (float*)d_out;
    int* flag = (int*)d_ws;

    (void)hipMemsetAsync(flag, 0, sizeof(int), stream);
    mask_flag_kernel<<<2048, 256, 0, stream>>>((const float4*)mask, flag);

    dim3 grid(S_LEN / BQ, 16);   // 32 q-tiles x (B*H) = 512 blocks
    attn_kernel<<<grid, 256, 0, stream>>>(Q, K, V, dk, mask, flag, out);
}

// Round 10
// 240.332 us; speedup vs baseline: 2.5242x; 1.0334x over previous
//
#include <hip/hip_runtime.h>

#define S_LEN 4096
#define DHEAD 64
#define BK    64       // K/V rows per tile
#define NT    (S_LEN / BK)
#define TILE_HALFS (BK * DHEAD)   // 4096 halfs / floats per tile

typedef __fp16   pk16x2 __attribute__((ext_vector_type(2)));
typedef _Float16 half8  __attribute__((ext_vector_type(8)));
typedef float    f32x16 __attribute__((ext_vector_type(16)));
typedef unsigned uint2v __attribute__((ext_vector_type(2)));

#define MFMA32(a, b, c) __builtin_amdgcn_mfma_f32_32x32x16_f16(a, b, c, 0, 0, 0)

__device__ __forceinline__ unsigned pk2u(float a, float b) {
    union { pk16x2 p; unsigned u; } x;
    x.p = __builtin_amdgcn_cvt_pkrtz(a, b);
    return x.u;
}

// permlane32_swap(x,y): r.x[l] = l<32 ? x[l] : y[l-32] ; r.y[l] = l<32 ? x[l+32] : y[l]
__device__ __forceinline__ uint2v pls(unsigned x, unsigned y) {
    return __builtin_amdgcn_permlane32_swap(x, y, false, false);
}
__device__ __forceinline__ float xmax32(float v) {
    uint2v r = pls(__float_as_uint(v), __float_as_uint(v));
    return fmaxf(__uint_as_float(r.x), __uint_as_float(r.y));
}
__device__ __forceinline__ float xadd32(float v) {
    uint2v r = pls(__float_as_uint(v), __float_as_uint(v));
    return __uint_as_float(r.x) + __uint_as_float(r.y);
}

// ---------------------------------------------------------------------------
// Pass 1: is the mask anywhere nonzero? 2048x256 threads, 8 float4/thread.
// ---------------------------------------------------------------------------
__global__ void mask_flag_kernel(const float4* __restrict__ mask, int* __restrict__ flag) {
    const long stride = 2048L * 256;
    long i = (long)blockIdx.x * 256 + threadIdx.x;
    int nz = 0;
    #pragma unroll
    for (int it = 0; it < 8; ++it) {
        float4 a = mask[i + it * stride];
        nz |= (a.x != 0.f) | (a.y != 0.f) | (a.z != 0.f) | (a.w != 0.f);
    }
    if (__any(nz)) {
        if ((threadIdx.x & 63) == 0) atomicOr(flag, 1);
    }
}

// ---------------------------------------------------------------------------
// Pass 2: flash attention. r9 champion frame (256 thr, 4 waves x 32 q-rows,
// inline fp32 staging, LDS dbuf, one barrier/tile, 2 blocks/CU) grafted with
// the r3-verified 32x32 inner loop: S^T = K.Q^T (lane owns one q-column), P
// redistributed to the PV A-operand fully in-register via permlane32_swap --
// NO P LDS round-trip (-12 DS ops/thread/tile, Pw buffer deleted, LDS 32 KB).
// THR=8 defer-max; s_setprio around MFMA clusters; XCD-chunked block decode
// (each XCD touches only 2 bh -> ~8x less K/V refetch).
//   KT[r][chunk c] = K[r][8*(c ^ (r&7)) .. +8]                (r7/r8-verified)
//   VT[d][chunk c] = V[8*(c ^ (d&7) ^ ((d>>3)&7)) + j][d]    (r7/r8-verified)
// ---------------------------------------------------------------------------
__global__ __launch_bounds__(256, 2) void attn32s_kernel(
    const float* __restrict__ Q, const float* __restrict__ K,
    const float* __restrict__ V, const int* __restrict__ dkp,
    const float* __restrict__ mask, const int* __restrict__ maskflag,
    float* __restrict__ O)
{
    const int bid = blockIdx.x;
    const int L   = (bid & 7) * 64 + (bid >> 3);   // XCD-chunked decode, 512 blocks
    const int bh  = L >> 5;                         // 0..15
    const int qt  = L & 31;                         // 0..31

    const int tid  = threadIdx.x;
    const int w    = tid >> 6;          // wave 0..3
    const int lane = tid & 63;
    const int l31  = lane & 31;
    const int h    = lane >> 5;
    const int cx   = lane & 7;                       // K read key (row l31)
    const int vkey = (l31 ^ (l31 >> 3)) & 7;         // V read key (row l31)

    const long gbase = (long)bh * S_LEN * DHEAD;
    const float* Qh = Q + gbase;
    const float* Kh = K + gbase;
    const float* Vh = V + gbase;

    const int q0 = qt * 128 + w * 32;               // this wave's 32 q-rows
    const float csq  = rsqrtf((float)dkp[0]) * 1.44269504088896f;
    const float mfac = -1e9f * 1.44269504088896f;
    const bool use_mask = (maskflag[0] != 0);

    __shared__ __align__(16) _Float16 KT[2][TILE_HALFS];   // 16 KB
    __shared__ __align__(16) _Float16 VT[2][TILE_HALFS];   // 16 KB

    // ---- Q B-operand frags, pre-scaled (lane -> Q[q0+l31][ks*16+8h+j]) ----
    half8 qf[4];
    #pragma unroll
    for (int ks = 0; ks < 4; ++ks) {
        const float4* src = (const float4*)(Qh + (long)(q0 + l31) * DHEAD + ks * 16 + h * 8);
        float4 a = src[0], b = src[1];
        union { unsigned u[4]; half8 h8; } u;
        u.u[0] = pk2u(a.x * csq, a.y * csq);
        u.u[1] = pk2u(a.z * csq, a.w * csq);
        u.u[2] = pk2u(b.x * csq, b.y * csq);
        u.u[3] = pk2u(b.z * csq, b.w * csq);
        qf[ks] = u.h8;
    }

    // ---- staging roles (r8-verified layouts) ----
    const int kr  = tid >> 2;            // K row 0..63
    const int ks4 = tid & 3;             // K 16-float segment
    const int vrp = tid >> 3;            // V row-pair 0..31
    const int vdq = tid & 7;             // V d-octet 0..7
    const float* Kb = Kh + (long)kr * DHEAD + ks4 * 16;
    const float* Vb = Vh + (long)(2 * vrp) * DHEAD + vdq * 8;
    const int kcol0 = (((2 * ks4)     ^ (kr & 7)) << 3);
    const int kcol1 = (((2 * ks4 + 1) ^ (kr & 7)) << 3);
    const int vd0   = vdq * 8;
    const int voct  = vrp >> 2;          // V row-octet
    const int vlow  = (2 * vrp) & 7;     // position within chunk

    float4 kf[4], vf[4];
    auto load_tile = [&](int kt) {
        const float4* kp  = (const float4*)(Kb + (long)kt * TILE_HALFS);
        kf[0] = kp[0]; kf[1] = kp[1]; kf[2] = kp[2]; kf[3] = kp[3];
        const float4* vp0 = (const float4*)(Vb + (long)kt * TILE_HALFS);
        const float4* vp1 = (const float4*)(Vb + (long)kt * TILE_HALFS + DHEAD);
        vf[0] = vp0[0]; vf[1] = vp0[1]; vf[2] = vp1[0]; vf[3] = vp1[1];
    };
    auto store_tile = [&](int bb) {
        union { unsigned u[4]; half8 h8; } u0, u1;
        u0.u[0] = pk2u(kf[0].x, kf[0].y);
        u0.u[1] = pk2u(kf[0].z, kf[0].w);
        u0.u[2] = pk2u(kf[1].x, kf[1].y);
        u0.u[3] = pk2u(kf[1].z, kf[1].w);
        u1.u[0] = pk2u(kf[2].x, kf[2].y);
        u1.u[1] = pk2u(kf[2].z, kf[2].w);
        u1.u[2] = pk2u(kf[3].x, kf[3].y);
        u1.u[3] = pk2u(kf[3].z, kf[3].w);
        *(half8*)&KT[bb][kr * 64 + kcol0] = u0.h8;
        *(half8*)&KT[bb][kr * 64 + kcol1] = u1.h8;
        _Float16* vt = &VT[bb][0];
        #define VCOL(j) ((((voct ^ (j) ^ vdq) & 7) << 3) + vlow)
        *(pk16x2*)&vt[(vd0 + 0) * 64 + VCOL(0)] = __builtin_amdgcn_cvt_pkrtz(vf[0].x, vf[2].x);
        *(pk16x2*)&vt[(vd0 + 1) * 64 + VCOL(1)] = __builtin_amdgcn_cvt_pkrtz(vf[0].y, vf[2].y);
        *(pk16x2*)&vt[(vd0 + 2) * 64 + VCOL(2)] = __builtin_amdgcn_cvt_pkrtz(vf[0].z, vf[2].z);
        *(pk16x2*)&vt[(vd0 + 3) * 64 + VCOL(3)] = __builtin_amdgcn_cvt_pkrtz(vf[0].w, vf[2].w);
        *(pk16x2*)&vt[(vd0 + 4) * 64 + VCOL(4)] = __builtin_amdgcn_cvt_pkrtz(vf[1].x, vf[3].x);
        *(pk16x2*)&vt[(vd0 + 5) * 64 + VCOL(5)] = __builtin_amdgcn_cvt_pkrtz(vf[1].y, vf[3].y);
        *(pk16x2*)&vt[(vd0 + 6) * 64 + VCOL(6)] = __builtin_amdgcn_cvt_pkrtz(vf[1].z, vf[3].z);
        *(pk16x2*)&vt[(vd0 + 7) * 64 + VCOL(7)] = __builtin_amdgcn_cvt_pkrtz(vf[1].w, vf[3].w);
        #undef VCOL
    };

    f32x16 o0 = {0.f,0.f,0.f,0.f,0.f,0.f,0.f,0.f,0.f,0.f,0.f,0.f,0.f,0.f,0.f,0.f};
    f32x16 o1 = o0;
    float m_i = -INFINITY;
    float l_i = 0.0f;

    load_tile(0);
    store_tile(0);
    __syncthreads();

    for (int kt = 0; kt < NT; ++kt) {
        const int b = kt & 1;
        if (kt + 1 < NT) load_tile(kt + 1);   // issue global prefetch

        // ---- S^T = K . Q^T : s0 = k-rows 0..31, s1 = k-rows 32..63 ----
        f32x16 s0 = {0.f,0.f,0.f,0.f,0.f,0.f,0.f,0.f,0.f,0.f,0.f,0.f,0.f,0.f,0.f,0.f};
        f32x16 s1 = s0;
        __builtin_amdgcn_s_setprio(1);
        #pragma unroll
        for (int ks = 0; ks < 4; ++ks) {
            const int off = (((2 * ks + h) ^ cx) << 3);
            half8 a0 = *(const half8*)&KT[b][(l31 << 6) + off];
            half8 a1 = *(const half8*)&KT[b][2048 + (l31 << 6) + off];
            s0 = MFMA32(a0, qf[ks], s0);
            s1 = MFMA32(a1, qf[ks], s1);
        }
        __builtin_amdgcn_s_setprio(0);

        // ---- stage next tile NOW (r8-verified placement): staging regs die
        // before softmax/PV; buffer b^1 unread during kt; barrier publishes.
        if (kt + 1 < NT) store_tile(b ^ 1);

        if (use_mask) {
            const float* mrow = mask + (long)(q0 + l31) * S_LEN + kt * BK;
            #pragma unroll
            for (int r = 0; r < 16; ++r) {
                const int k = (r & 3) + ((r >> 2) << 3) + (h << 2);
                s0[r] += mfac * mrow[k];
                s1[r] += mfac * mrow[32 + k];
            }
        }

        // ---- online softmax (exp2 domain), THR=8 defer-max ----
        {
            float tt[8];
            #pragma unroll
            for (int i = 0; i < 8; ++i)
                tt[i] = fmaxf(fmaxf(s0[2*i], s0[2*i+1]), fmaxf(s1[2*i], s1[2*i+1]));
            float mx = fmaxf(fmaxf(fmaxf(tt[0], tt[1]), fmaxf(tt[2], tt[3])),
                             fmaxf(fmaxf(tt[4], tt[5]), fmaxf(tt[6], tt[7])));
            mx = xmax32(mx);                               // VALU, not DS
            const bool need = __any(mx > m_i + 8.0f);      // wave-uniform
            const float mnew = need ? fmaxf(m_i, mx) : m_i;
            float ra = 0.f, rb = 0.f;
            #pragma unroll
            for (int r = 0; r < 16; ++r) {
                float p0 = __builtin_amdgcn_exp2f(s0[r] - mnew);
                float p1 = __builtin_amdgcn_exp2f(s1[r] - mnew);
                s0[r] = p0; s1[r] = p1;
                ra += p0; rb += p1;
            }
            float rsum = xadd32(ra + rb);
            if (need) {
                const float alpha = __builtin_amdgcn_exp2f(m_i - mnew);
                #pragma unroll
                for (int r = 0; r < 16; ++r) {
                    const int qr = (r & 3) + ((r >> 2) << 3) + (h << 2);
                    float a_r = __shfl(alpha, qr, 64);
                    o0[r] *= a_r; o1[r] *= a_r;
                }
                l_i = alpha * l_i + rsum;
                m_i = mnew;
            } else {
                l_i += rsum;
            }
        }

        // ---- P words -> PV A-operand fully in-register (pls direct) ----
        unsigned wp[16];
        #pragma unroll
        for (int d = 0; d < 8; ++d) {
            wp[d]     = pk2u(s0[2*d], s0[2*d+1]);
            wp[8 + d] = pk2u(s1[2*d], s1[2*d+1]);
        }

        __builtin_amdgcn_s_setprio(1);
        #pragma unroll
        for (int si = 0; si < 4; ++si) {
            const int bs = (si >> 1) * 8 + (si & 1) * 4;
            uint2v r0 = pls(wp[bs + 0], wp[bs + 2]);
            uint2v r1 = pls(wp[bs + 1], wp[bs + 3]);
            union { unsigned u[4]; half8 h8; } pa;
            pa.u[0] = r0.x; pa.u[1] = r1.x; pa.u[2] = r0.y; pa.u[3] = r1.y;
            const int voff = (((2 * si + h) ^ vkey) << 3);
            half8 v0 = *(const half8*)&VT[b][(l31 << 6) + voff];
            half8 v1 = *(const half8*)&VT[b][2048 + (l31 << 6) + (voff ^ 32)];
            o0 = MFMA32(pa.h8, v0, o0);
            o1 = MFMA32(pa.h8, v1, o1);
        }
        __builtin_amdgcn_s_setprio(0);

        if (kt + 1 < NT) __syncthreads();    // publish b^1 for next iteration
    }

    // ---- epilogue: O /= l (lane qr owns row qr's l) ----
    float* dst = O + gbase;
    #pragma unroll
    for (int r = 0; r < 16; ++r) {
        const int qr = (r & 3) + ((r >> 2) << 3) + (h << 2);
        float lq = __shfl(l_i, qr, 64);
        float inv = __builtin_amdgcn_rcpf(lq);
        const long row = (long)(q0 + qr) * DHEAD;
        dst[row + l31]      = o0[r] * inv;
        dst[row + 32 + l31] = o1[r] * inv;
    }
}

extern "C" void kernel_launch(void* const* d_in, const int* in_sizes, int n_in,
                              void* d_out, int out_size, void* d_ws, size_t ws_size,
                              hipStream_t stream) {
    const float* Q    = (const float*)d_in[0];
    const float* K    = (const float*)d_in[1];
    const float* V    = (const float*)d_in[2];
    const int*   dk   = (const int*)d_in[3];
    const float* mask = (const float*)d_in[4];
    float* out = (float*)d_out;
    int* flag = (int*)d_ws;

    (void)hipMemsetAsync(flag, 0, sizeof(int), stream);
    mask_flag_kernel<<<2048, 256, 0, stream>>>((const float4*)mask, flag);

    attn32s_kernel<<<512, 256, 0, stream>>>(Q, K, V, dk, mask, flag, out);
}